// Round 20
// baseline (1370.456 us; speedup 1.0000x reference)
//
#include <hip/hip_runtime.h>
#include <hip/hip_cooperative_groups.h>

namespace cg = cooperative_groups;

#define BB 32
#define CC 128
#define HH 128
#define WW 128
#define HWSZ (HH * WW)          // 16384
#define CHW (CC * HWSZ)         // 2097152
#define S4 (HWSZ / 4)           // 4096

typedef float vfloat4 __attribute__((ext_vector_type(4)));

__device__ __forceinline__ vfloat4 fmax4(vfloat4 a, vfloat4 b) {
    vfloat4 r;
    r.x = fmaxf(a.x, b.x);
    r.y = fmaxf(a.y, b.y);
    r.z = fmaxf(a.z, b.z);
    r.w = fmaxf(a.w, b.w);
    return r;
}

// ============ PLAN A: persistent coop kernel, x read ONCE, slab in LDS ======
// 256 blocks x 1024 threads, 1 block/CU (153.5 KiB LDS). 8 gens x 4 batches.
// Band = 2 rows. Slab lives in LDS (spill-proof; R18/R19 register slabs both
// spilled to scratch and cost 3.5-5x).
__global__ __launch_bounds__(1024, 4) void sa_coop(
    const float* __restrict__ x, const float* __restrict__ cw,
    float* __restrict__ out, float* __restrict__ maps) {
    __shared__ float slab[2][CC][WW];    // [r][c][w] 128 KiB
    __shared__ float psum_s[8][2][WW];   // [cg2][r][w] 8 KiB
    __shared__ float psum_m[8][2][WW];   // 8 KiB
    __shared__ float m_lds[2][8][WW];    // halo rows (gh = h0-3+idx) 8 KiB
    __shared__ float sig_lds[2][WW];     // 1 KiB
    __shared__ float wsh[2 * 49];

    const int tid = threadIdx.x;
    const int blk = blockIdx.x;          // 0..255
    const int xcd = blk & 7;
    const int lin = blk >> 3;            // 0..31
    const int bq  = lin >> 3;            // 0..3  batch within generation
    const int band = xcd * 8 + (lin & 7);// 0..63
    const int h0 = band * 2;

    const int wave = tid >> 6;           // 0..15
    const int lane = tid & 63;
    const int r    = wave & 1;           // row in band
    const int cg2  = wave >> 1;          // 0..7 channel group (16 ch)
    const int half = lane >> 5;          // 0/1 -> +8 channels
    const int w4   = lane & 31;          // float4 column
    const int c0   = cg2 * 16 + half * 8;

    if (tid < 98) wsh[tid] = cw[tid];

    cg::grid_group grid = cg::this_grid();

    for (int g = 0; g < 8; ++g) {
        __syncthreads();                 // slab/sig/m_lds reuse across gens
        const int b = g * 4 + bq;
        const float* xb = x + (size_t)b * CHW;

        // ---- Phase A: stream 8 channels -> slab LDS + partial reduce ----
        {
            const float* base = xb + (size_t)c0 * HWSZ + (h0 + r) * WW;
            vfloat4 s, m;
            #pragma unroll
            for (int i = 0; i < 8; ++i) {
                vfloat4 t = __builtin_nontemporal_load(
                    (const vfloat4*)(base + (size_t)i * HWSZ) + w4);
                *(vfloat4*)&slab[r][c0 + i][w4 * 4] = t;
                if (i == 0) { s = t; m = t; }
                else        { s += t; m = fmax4(m, t); }
            }
            // fold the two halves (lane ^ 32) in-register
            s.x += __shfl_xor(s.x, 32); s.y += __shfl_xor(s.y, 32);
            s.z += __shfl_xor(s.z, 32); s.w += __shfl_xor(s.w, 32);
            m.x = fmaxf(m.x, __shfl_xor(m.x, 32));
            m.y = fmaxf(m.y, __shfl_xor(m.y, 32));
            m.z = fmaxf(m.z, __shfl_xor(m.z, 32));
            m.w = fmaxf(m.w, __shfl_xor(m.w, 32));
            if (half == 0) {
                *(vfloat4*)&psum_s[cg2][r][w4 * 4] = s;
                *(vfloat4*)&psum_m[cg2][r][w4 * 4] = m;
            }
        }
        __syncthreads();
        if (tid < 64) {                  // combine 8 groups; publish maps
            const int rr = tid >> 5, wb = tid & 31;
            vfloat4 s = *(vfloat4*)&psum_s[0][rr][wb * 4];
            vfloat4 m = *(vfloat4*)&psum_m[0][rr][wb * 4];
            #pragma unroll
            for (int c = 1; c < 8; ++c) {
                s += *(vfloat4*)&psum_s[c][rr][wb * 4];
                m = fmax4(m, *(vfloat4*)&psum_m[c][rr][wb * 4]);
            }
            vfloat4 avg = s * (1.0f / (float)CC);
            *(vfloat4*)&m_lds[0][3 + rr][wb * 4] = avg;   // own rows idx 3,4
            *(vfloat4*)&m_lds[1][3 + rr][wb * 4] = m;
            *((vfloat4*)(maps + ((size_t)b * 2 + 0) * HWSZ + (h0 + rr) * WW) + wb) = avg;
            *((vfloat4*)(maps + ((size_t)b * 2 + 1) * HWSZ + (h0 + rr) * WW) + wb) = m;
        }
        __threadfence();
        grid.sync();                     // all maps of this generation visible

        // ---- Phase B: stage 6 neighbor halo rows + conv + sigmoid ----
        if (tid < 384) {                 // 2 ic x 6 rows x 32 w4
            const int ic = tid / 192;
            const int rem = tid - ic * 192;
            const int ridx = rem >> 5;   // 0..5
            const int wb = rem & 31;
            const int rr = (ridx < 3) ? ridx : ridx + 2;   // idx 0,1,2,5,6,7
            const int gh = h0 - 3 + rr;
            vfloat4 val = {0.f, 0.f, 0.f, 0.f};
            if (gh >= 0 && gh < HH)
                val = *((const vfloat4*)(maps + ((size_t)b * 2 + ic) * HWSZ + gh * WW) + wb);
            *(vfloat4*)&m_lds[ic][rr][wb * 4] = val;
        }
        __syncthreads();
        if (tid < 256) {                 // 2 rows x 128 cols, one output each
            const int rr = tid >> 7;
            const int w = tid & 127;
            float attn = 0.f;
            #pragma unroll
            for (int ic = 0; ic < 2; ++ic) {
                #pragma unroll
                for (int kh = 0; kh < 7; ++kh) {
                    const float* row = &m_lds[ic][rr + kh][0];
                    #pragma unroll
                    for (int kw = 0; kw < 7; ++kw) {
                        int wi = w - 3 + kw;
                        float vv = (wi >= 0 && wi < WW) ? row[wi] : 0.0f;
                        attn = fmaf(vv, wsh[ic * 49 + kh * 7 + kw], attn);
                    }
                }
            }
            sig_lds[rr][w] = 1.0f / (1.0f + __expf(-attn));
        }
        __syncthreads();

        // ---- Phase C: multiply slab from LDS, nt-store ----
        {
            vfloat4 sg = *(const vfloat4*)&sig_lds[r][w4 * 4];
            float* ob = out + (size_t)b * CHW + (size_t)c0 * HWSZ + (h0 + r) * WW;
            #pragma unroll
            for (int i = 0; i < 8; ++i) {
                vfloat4 t = *(vfloat4*)&slab[r][c0 + i][w4 * 4];
                __builtin_nontemporal_store(t * sg, (vfloat4*)(ob + (size_t)i * HWSZ) + w4);
            }
        }
    }
}

// =================== PLAN B: R12 champion (two kernels) ===================
#define RPB 8
#define HALO 14

__global__ __launch_bounds__(256) void k1_reduce(
    const float* __restrict__ x, float* __restrict__ maps) {
    const int tid = threadIdx.x;
    const int wg  = blockIdx.x;
    const int b   = wg >> 4;
    const int hb  = wg & 15;
    const int gh  = hb * RPB + (tid >> 5);
    const int w4  = tid & 31;

    const vfloat4* p = (const vfloat4*)(x + (size_t)b * CHW + gh * WW) + w4;
    vfloat4 v = p[0];
    vfloat4 sum = v, mx = v;
    #pragma unroll 8
    for (int c = 1; c < CC; ++c) {
        vfloat4 t = p[(size_t)c * S4];
        sum += t;
        mx = fmax4(mx, t);
    }
    vfloat4 avg = sum * (1.0f / (float)CC);
    *((vfloat4*)(maps + ((size_t)b * 2 + 0) * HWSZ + gh * WW) + w4) = avg;
    *((vfloat4*)(maps + ((size_t)b * 2 + 1) * HWSZ + gh * WW) + w4) = mx;
}

__global__ __launch_bounds__(256, 2) void k2_conv_mul(
    const float* __restrict__ x, const float* __restrict__ maps,
    const float* __restrict__ cw, float* __restrict__ out) {
    __shared__ float m_lds[2][HALO][WW];
    __shared__ float sig_lds[RPB][WW];
    __shared__ float wsh[2 * 49];

    const int tid = threadIdx.x;
    const int wg  = blockIdx.x;
    const int xcd = wg & 7;
    const int lin = wg >> 3;
    const int b   = xcd * 4 + (lin >> 4);
    const int hb  = lin & 15;
    const int h0  = hb * RPB;

    if (tid < 98) wsh[tid] = cw[tid];

    for (int i = tid; i < 2 * HALO * 32; i += 256) {
        const int ic = i / (HALO * 32);
        const int rem = i - ic * (HALO * 32);
        const int rr = rem >> 5;
        const int w4 = rem & 31;
        const int gh = h0 - 3 + rr;
        vfloat4 v = {0.f, 0.f, 0.f, 0.f};
        if (gh >= 0 && gh < HH)
            v = *((const vfloat4*)(maps + ((size_t)b * 2 + ic) * HWSZ + gh * WW) + w4);
        *(vfloat4*)&m_lds[ic][rr][w4 * 4] = v;
    }
    __syncthreads();

    {
        const int q = tid >> 7;
        const int w = tid & 127;
        float attn[4] = {0.f, 0.f, 0.f, 0.f};
        #pragma unroll
        for (int ic = 0; ic < 2; ++ic) {
            #pragma unroll
            for (int L = 0; L < 10; ++L) {
                const float* row = &m_lds[ic][q * 4 + L][0];
                #pragma unroll
                for (int kw = 0; kw < 7; ++kw) {
                    int wi = w - 3 + kw;
                    float v = (wi >= 0 && wi < WW) ? row[wi] : 0.0f;
                    #pragma unroll
                    for (int j = 0; j < 4; ++j) {
                        const int kh = L - j;
                        if (kh >= 0 && kh <= 6)
                            attn[j] = fmaf(v, wsh[ic * 49 + kh * 7 + kw], attn[j]);
                    }
                }
            }
        }
        #pragma unroll
        for (int j = 0; j < 4; ++j)
            sig_lds[q * 4 + j][w] = 1.0f / (1.0f + __expf(-attn[j]));
    }
    __syncthreads();

    {
        const float* xb = x + (size_t)b * CHW;
        const int wv = tid >> 6;
        const int ln = tid & 63;
        vfloat4 sgv[4];
        #pragma unroll
        for (int j = 0; j < 4; ++j) {
            int idx = ln + 64 * j;
            sgv[j] = *(const vfloat4*)&sig_lds[idx >> 5][(idx & 31) * 4];
        }
        const size_t slab_off = (size_t)h0 * WW;
        #pragma unroll 2
        for (int k = 31; k >= 0; --k) {
            const int c = wv + 4 * k;
            const vfloat4* ps = (const vfloat4*)(xb + (size_t)c * HWSZ + slab_off);
            vfloat4* po = (vfloat4*)(out + (size_t)b * CHW + (size_t)c * HWSZ + slab_off);
            vfloat4 v0 = ps[ln];
            vfloat4 v1 = ps[ln + 64];
            vfloat4 v2 = ps[ln + 128];
            vfloat4 v3 = ps[ln + 192];
            __builtin_nontemporal_store(v0 * sgv[0], po + ln);
            __builtin_nontemporal_store(v1 * sgv[1], po + ln + 64);
            __builtin_nontemporal_store(v2 * sgv[2], po + ln + 128);
            __builtin_nontemporal_store(v3 * sgv[3], po + ln + 192);
        }
    }
}

// =================== FALLBACK (ws < 4 MiB): fused champion ===================
__global__ __launch_bounds__(256, 2) void sa_onepass(
    const float* __restrict__ x, const float* __restrict__ cw,
    float* __restrict__ out) {
    __shared__ float m_lds[2][HALO][WW];
    __shared__ float sig_lds[RPB][WW];
    __shared__ float wsh[2 * 49];

    const int tid = threadIdx.x;
    const int wg  = blockIdx.x;
    const int xcd = wg & 7;
    const int lin = wg >> 3;
    const int b   = xcd * 4 + (lin >> 4);
    const int hb  = lin & 15;
    const int h0  = hb * RPB;

    if (tid < 98) wsh[tid] = cw[tid];

    const int r0 = tid >> 5;
    const int w4 = tid & 31;
    const float* xb = x + (size_t)b * CHW;

    const bool actB = (r0 < HALO - 8);
    const int gh_a = h0 - 3 + r0;
    const int gh_b = h0 - 3 + r0 + 8;
    const bool okA = (gh_a >= 0) && (gh_a < HH);
    const bool okB = actB && (gh_b < HH);
    const int cha = gh_a < 0 ? 0 : (gh_a > HH - 1 ? HH - 1 : gh_a);
    const int chb = gh_b > HH - 1 ? HH - 1 : gh_b;

    const vfloat4* pA = (const vfloat4*)(xb + cha * WW) + w4;
    const vfloat4* pB = (const vfloat4*)(xb + chb * WW) + w4;

    vfloat4 sumA, mxA;
    {
        vfloat4 v = pA[0];
        sumA = v; mxA = v;
    }
    #pragma unroll 8
    for (int c = 1; c < CC; ++c) {
        vfloat4 v = pA[(size_t)c * S4];
        sumA += v;
        mxA = fmax4(mxA, v);
    }
    vfloat4 sumB = {0.f, 0.f, 0.f, 0.f}, mxB = sumB;
    if (actB) {
        vfloat4 v = pB[0];
        sumB = v; mxB = v;
        #pragma unroll 8
        for (int c = 1; c < CC; ++c) {
            vfloat4 t = pB[(size_t)c * S4];
            sumB += t;
            mxB = fmax4(mxB, t);
        }
    }

    const float invC = 1.0f / (float)CC;
    {
        vfloat4 avgA = sumA * invC;
        if (!okA) { avgA = (vfloat4){0,0,0,0}; mxA = (vfloat4){0,0,0,0}; }
        *(vfloat4*)&m_lds[0][r0][w4 * 4] = avgA;
        *(vfloat4*)&m_lds[1][r0][w4 * 4] = mxA;
        if (actB) {
            vfloat4 avgB = sumB * invC;
            if (!okB) { avgB = (vfloat4){0,0,0,0}; mxB = (vfloat4){0,0,0,0}; }
            *(vfloat4*)&m_lds[0][r0 + 8][w4 * 4] = avgB;
            *(vfloat4*)&m_lds[1][r0 + 8][w4 * 4] = mxB;
        }
    }
    __syncthreads();

    {
        const int q = tid >> 7;
        const int w = tid & 127;
        float attn[4] = {0.f, 0.f, 0.f, 0.f};
        #pragma unroll
        for (int ic = 0; ic < 2; ++ic) {
            #pragma unroll
            for (int L = 0; L < 10; ++L) {
                const float* row = &m_lds[ic][q * 4 + L][0];
                #pragma unroll
                for (int kw = 0; kw < 7; ++kw) {
                    int wi = w - 3 + kw;
                    float v = (wi >= 0 && wi < WW) ? row[wi] : 0.0f;
                    #pragma unroll
                    for (int j = 0; j < 4; ++j) {
                        const int kh = L - j;
                        if (kh >= 0 && kh <= 6)
                            attn[j] = fmaf(v, wsh[ic * 49 + kh * 7 + kw], attn[j]);
                    }
                }
            }
        }
        #pragma unroll
        for (int j = 0; j < 4; ++j)
            sig_lds[q * 4 + j][w] = 1.0f / (1.0f + __expf(-attn[j]));
    }
    __syncthreads();

    {
        const int wv = tid >> 6;
        const int ln = tid & 63;
        vfloat4 sgv[4];
        #pragma unroll
        for (int j = 0; j < 4; ++j) {
            int idx = ln + 64 * j;
            sgv[j] = *(const vfloat4*)&sig_lds[idx >> 5][(idx & 31) * 4];
        }
        const size_t slab_off = (size_t)h0 * WW;
        #pragma unroll 2
        for (int k = 31; k >= 0; --k) {
            const int c = wv + 4 * k;
            const vfloat4* ps = (const vfloat4*)(xb + (size_t)c * HWSZ + slab_off);
            vfloat4* po = (vfloat4*)(out + (size_t)b * CHW + (size_t)c * HWSZ + slab_off);
            vfloat4 v0 = ps[ln];
            vfloat4 v1 = ps[ln + 64];
            vfloat4 v2 = ps[ln + 128];
            vfloat4 v3 = ps[ln + 192];
            __builtin_nontemporal_store(v0 * sgv[0], po + ln);
            __builtin_nontemporal_store(v1 * sgv[1], po + ln + 64);
            __builtin_nontemporal_store(v2 * sgv[2], po + ln + 128);
            __builtin_nontemporal_store(v3 * sgv[3], po + ln + 192);
        }
    }
}

extern "C" void kernel_launch(void* const* d_in, const int* in_sizes, int n_in,
                              void* d_out, int out_size, void* d_ws, size_t ws_size,
                              hipStream_t stream) {
    const float* x  = (const float*)d_in[0];
    const float* cw = (const float*)d_in[1];
    float* out = (float*)d_out;

    const size_t maps_bytes = (size_t)BB * 2 * HWSZ * sizeof(float);  // 4 MiB
    if (ws_size >= maps_bytes) {
        float* maps = (float*)d_ws;
        void* args[] = {(void*)&x, (void*)&cw, (void*)&out, (void*)&maps};
        hipError_t e = hipLaunchCooperativeKernel((void*)sa_coop, dim3(256), dim3(1024),
                                                  args, 0, stream);
        if (e != hipSuccess) {
            // deterministic fallback: R12 champion path
            k1_reduce<<<BB * (HH / RPB), 256, 0, stream>>>(x, maps);
            k2_conv_mul<<<BB * (HH / RPB), 256, 0, stream>>>(x, maps, cw, out);
        }
    } else {
        sa_onepass<<<BB * (HH / RPB), 256, 0, stream>>>(x, cw, out);
    }
}

// Round 21
// 132.923 us; speedup vs baseline: 10.3102x; 10.3102x over previous
//
#include <hip/hip_runtime.h>

#define BB 32
#define CC 128
#define HH 128
#define WW 128
#define HWSZ (HH * WW)          // 16384
#define CHW (CC * HWSZ)         // 2097152
#define S4 (HWSZ / 4)           // 4096
#define RPB 8                   // rows per block
#define HALO 14                 // RPB + 6

typedef float vfloat4 __attribute__((ext_vector_type(4)));

__device__ __forceinline__ vfloat4 fmax4(vfloat4 a, vfloat4 b) {
    vfloat4 r;
    r.x = fmaxf(a.x, b.x);
    r.y = fmaxf(a.y, b.y);
    r.z = fmaxf(a.z, b.z);
    r.w = fmaxf(a.w, b.w);
    return r;
}

// =================== PLAN A (ws >= 4 MiB): two kernels ===================
// R12 champion: 133.1 us measured. Issued traffic 815 MB @ ~6.1-7 TB/s.
// Ledger: occupancy up (R6/R17) hurts; nt stores win +34us (R7); bank
// conflicts/bursts null (R8/R11); split K2-multiply from K1 (R9) hurts via
// L3 reuse-distance; x-once coop variants (R18-R20) lose 3.5-10x.

// K1: each row reduced exactly ONCE (no halo redundancy). 512 blocks.
// maps layout: [B][2][HH][WW] (ic 0 = avg, 1 = max).
__global__ __launch_bounds__(256) void k1_reduce(
    const float* __restrict__ x, float* __restrict__ maps) {
    const int tid = threadIdx.x;
    const int wg  = blockIdx.x;            // 0..511
    const int b   = wg >> 4;
    const int hb  = wg & 15;
    const int gh  = hb * RPB + (tid >> 5); // global row
    const int w4  = tid & 31;

    const vfloat4* p = (const vfloat4*)(x + (size_t)b * CHW + gh * WW) + w4;
    vfloat4 v = p[0];
    vfloat4 sum = v, mx = v;
    #pragma unroll 8
    for (int c = 1; c < CC; ++c) {
        vfloat4 t = p[(size_t)c * S4];
        sum += t;
        mx = fmax4(mx, t);
    }
    vfloat4 avg = sum * (1.0f / (float)CC);
    *((vfloat4*)(maps + ((size_t)b * 2 + 0) * HWSZ + gh * WW) + w4) = avg;
    *((vfloat4*)(maps + ((size_t)b * 2 + 1) * HWSZ + gh * WW) + w4) = mx;
}

// K2: stage 14 map-rows from global -> conv+sigmoid -> channel-major multiply.
// bounds (256,2): 2 blocks/CU is the measured sweet spot (4 regressed 26%, R17).
__global__ __launch_bounds__(256, 2) void k2_conv_mul(
    const float* __restrict__ x, const float* __restrict__ maps,
    const float* __restrict__ cw, float* __restrict__ out) {
    __shared__ float m_lds[2][HALO][WW];   // 14 KiB
    __shared__ float sig_lds[RPB][WW];     // 4 KiB
    __shared__ float wsh[2 * 49];

    const int tid = threadIdx.x;
    // XCD swizzle: adjacent bands of a batch share an XCD.
    const int wg  = blockIdx.x;            // 0..511
    const int xcd = wg & 7;
    const int lin = wg >> 3;               // 0..63
    const int b   = xcd * 4 + (lin >> 4);  // 0..31
    const int hb  = lin & 15;              // 0..15
    const int h0  = hb * RPB;

    if (tid < 98) wsh[tid] = cw[tid];

    // ---- stage map halo rows h0-3 .. h0+10 (zero-fill OOB) ----
    for (int i = tid; i < 2 * HALO * 32; i += 256) {
        const int ic = i / (HALO * 32);
        const int rem = i - ic * (HALO * 32);
        const int rr = rem >> 5;           // 0..13
        const int w4 = rem & 31;
        const int gh = h0 - 3 + rr;
        vfloat4 v = {0.f, 0.f, 0.f, 0.f};
        if (gh >= 0 && gh < HH)
            v = *((const vfloat4*)(maps + ((size_t)b * 2 + ic) * HWSZ + gh * WW) + w4);
        *(vfloat4*)&m_lds[ic][rr][w4 * 4] = v;
    }
    __syncthreads();

    // ---- conv 7x7 + sigmoid, conflict-free (R8 layout) ----
    {
        const int q = tid >> 7;            // 0..1 -> rows q*4 .. q*4+3
        const int w = tid & 127;
        float attn[4] = {0.f, 0.f, 0.f, 0.f};
        #pragma unroll
        for (int ic = 0; ic < 2; ++ic) {
            #pragma unroll
            for (int L = 0; L < 10; ++L) {
                const float* row = &m_lds[ic][q * 4 + L][0];
                #pragma unroll
                for (int kw = 0; kw < 7; ++kw) {
                    int wi = w - 3 + kw;
                    float v = (wi >= 0 && wi < WW) ? row[wi] : 0.0f;
                    #pragma unroll
                    for (int j = 0; j < 4; ++j) {
                        const int kh = L - j;
                        if (kh >= 0 && kh <= 6)
                            attn[j] = fmaf(v, wsh[ic * 49 + kh * 7 + kw], attn[j]);
                    }
                }
            }
        }
        #pragma unroll
        for (int j = 0; j < 4; ++j)
            sig_lds[q * 4 + j][w] = 1.0f / (1.0f + __expf(-attn[j]));
    }
    __syncthreads();

    // ---- phase 3: channel-major waves, 4 KB contiguous bursts, nt stores ----
    {
        const float* xb = x + (size_t)b * CHW;
        const int wv = tid >> 6;           // 0..3
        const int ln = tid & 63;
        vfloat4 sgv[4];
        #pragma unroll
        for (int j = 0; j < 4; ++j) {
            int idx = ln + 64 * j;
            sgv[j] = *(const vfloat4*)&sig_lds[idx >> 5][(idx & 31) * 4];
        }
        const size_t slab_off = (size_t)h0 * WW;
        #pragma unroll 2
        for (int k = 31; k >= 0; --k) {
            const int c = wv + 4 * k;
            const vfloat4* ps = (const vfloat4*)(xb + (size_t)c * HWSZ + slab_off);
            vfloat4* po = (vfloat4*)(out + (size_t)b * CHW + (size_t)c * HWSZ + slab_off);
            vfloat4 v0 = ps[ln];
            vfloat4 v1 = ps[ln + 64];
            vfloat4 v2 = ps[ln + 128];
            vfloat4 v3 = ps[ln + 192];
            __builtin_nontemporal_store(v0 * sgv[0], po + ln);
            __builtin_nontemporal_store(v1 * sgv[1], po + ln + 64);
            __builtin_nontemporal_store(v2 * sgv[2], po + ln + 128);
            __builtin_nontemporal_store(v3 * sgv[3], po + ln + 192);
        }
    }
}

// =================== FALLBACK (ws < 4 MiB): fused champion ===================
__global__ __launch_bounds__(256, 2) void sa_onepass(
    const float* __restrict__ x, const float* __restrict__ cw,
    float* __restrict__ out) {
    __shared__ float m_lds[2][HALO][WW];
    __shared__ float sig_lds[RPB][WW];
    __shared__ float wsh[2 * 49];

    const int tid = threadIdx.x;
    const int wg  = blockIdx.x;
    const int xcd = wg & 7;
    const int lin = wg >> 3;
    const int b   = xcd * 4 + (lin >> 4);
    const int hb  = lin & 15;
    const int h0  = hb * RPB;

    if (tid < 98) wsh[tid] = cw[tid];

    const int r0 = tid >> 5;
    const int w4 = tid & 31;
    const float* xb = x + (size_t)b * CHW;

    const bool actB = (r0 < HALO - 8);
    const int gh_a = h0 - 3 + r0;
    const int gh_b = h0 - 3 + r0 + 8;
    const bool okA = (gh_a >= 0) && (gh_a < HH);
    const bool okB = actB && (gh_b < HH);
    const int cha = gh_a < 0 ? 0 : (gh_a > HH - 1 ? HH - 1 : gh_a);
    const int chb = gh_b > HH - 1 ? HH - 1 : gh_b;

    const vfloat4* pA = (const vfloat4*)(xb + cha * WW) + w4;
    const vfloat4* pB = (const vfloat4*)(xb + chb * WW) + w4;

    vfloat4 sumA, mxA;
    {
        vfloat4 v = pA[0];
        sumA = v; mxA = v;
    }
    #pragma unroll 8
    for (int c = 1; c < CC; ++c) {
        vfloat4 v = pA[(size_t)c * S4];
        sumA += v;
        mxA = fmax4(mxA, v);
    }
    vfloat4 sumB = {0.f, 0.f, 0.f, 0.f}, mxB = sumB;
    if (actB) {
        vfloat4 v = pB[0];
        sumB = v; mxB = v;
        #pragma unroll 8
        for (int c = 1; c < CC; ++c) {
            vfloat4 t = pB[(size_t)c * S4];
            sumB += t;
            mxB = fmax4(mxB, t);
        }
    }

    const float invC = 1.0f / (float)CC;
    {
        vfloat4 avgA = sumA * invC;
        if (!okA) { avgA = (vfloat4){0,0,0,0}; mxA = (vfloat4){0,0,0,0}; }
        *(vfloat4*)&m_lds[0][r0][w4 * 4] = avgA;
        *(vfloat4*)&m_lds[1][r0][w4 * 4] = mxA;
        if (actB) {
            vfloat4 avgB = sumB * invC;
            if (!okB) { avgB = (vfloat4){0,0,0,0}; mxB = (vfloat4){0,0,0,0}; }
            *(vfloat4*)&m_lds[0][r0 + 8][w4 * 4] = avgB;
            *(vfloat4*)&m_lds[1][r0 + 8][w4 * 4] = mxB;
        }
    }
    __syncthreads();

    {
        const int q = tid >> 7;
        const int w = tid & 127;
        float attn[4] = {0.f, 0.f, 0.f, 0.f};
        #pragma unroll
        for (int ic = 0; ic < 2; ++ic) {
            #pragma unroll
            for (int L = 0; L < 10; ++L) {
                const float* row = &m_lds[ic][q * 4 + L][0];
                #pragma unroll
                for (int kw = 0; kw < 7; ++kw) {
                    int wi = w - 3 + kw;
                    float v = (wi >= 0 && wi < WW) ? row[wi] : 0.0f;
                    #pragma unroll
                    for (int j = 0; j < 4; ++j) {
                        const int kh = L - j;
                        if (kh >= 0 && kh <= 6)
                            attn[j] = fmaf(v, wsh[ic * 49 + kh * 7 + kw], attn[j]);
                    }
                }
            }
        }
        #pragma unroll
        for (int j = 0; j < 4; ++j)
            sig_lds[q * 4 + j][w] = 1.0f / (1.0f + __expf(-attn[j]));
    }
    __syncthreads();

    {
        const int wv = tid >> 6;
        const int ln = tid & 63;
        vfloat4 sgv[4];
        #pragma unroll
        for (int j = 0; j < 4; ++j) {
            int idx = ln + 64 * j;
            sgv[j] = *(const vfloat4*)&sig_lds[idx >> 5][(idx & 31) * 4];
        }
        const size_t slab_off = (size_t)h0 * WW;
        #pragma unroll 2
        for (int k = 31; k >= 0; --k) {
            const int c = wv + 4 * k;
            const vfloat4* ps = (const vfloat4*)(xb + (size_t)c * HWSZ + slab_off);
            vfloat4* po = (vfloat4*)(out + (size_t)b * CHW + (size_t)c * HWSZ + slab_off);
            vfloat4 v0 = ps[ln];
            vfloat4 v1 = ps[ln + 64];
            vfloat4 v2 = ps[ln + 128];
            vfloat4 v3 = ps[ln + 192];
            __builtin_nontemporal_store(v0 * sgv[0], po + ln);
            __builtin_nontemporal_store(v1 * sgv[1], po + ln + 64);
            __builtin_nontemporal_store(v2 * sgv[2], po + ln + 128);
            __builtin_nontemporal_store(v3 * sgv[3], po + ln + 192);
        }
    }
}

extern "C" void kernel_launch(void* const* d_in, const int* in_sizes, int n_in,
                              void* d_out, int out_size, void* d_ws, size_t ws_size,
                              hipStream_t stream) {
    const float* x  = (const float*)d_in[0];
    const float* cw = (const float*)d_in[1];
    float* out = (float*)d_out;

    const size_t maps_bytes = (size_t)BB * 2 * HWSZ * sizeof(float);  // 4 MiB
    if (ws_size >= maps_bytes) {
        float* maps = (float*)d_ws;
        k1_reduce<<<BB * (HH / RPB), 256, 0, stream>>>(x, maps);
        k2_conv_mul<<<BB * (HH / RPB), 256, 0, stream>>>(x, maps, cw, out);
    } else {
        sa_onepass<<<BB * (HH / RPB), 256, 0, stream>>>(x, cw, out);
    }
}